// Round 19
// baseline (110.857 us; speedup 1.0000x reference)
//
#include <hip/hip_runtime.h>

#define EPS 1e-20f
typedef float f4 __attribute__((ext_vector_type(4)));

// ws layout (floats): [0,288)   sw  = softplus(spatial_weight) [c*9+k]
//                     [288,1312) cwT = softplus(channel_weight) transposed [c*32+o]
//                     [1312] 1/sum(sw), [1313] 1/sum(cw)
__global__ void prep_weights(const float* __restrict__ channel_weight, // [32*32] = [o][c]
                             const float* __restrict__ spatial_weight, // [32*9]
                             float* __restrict__ ws) {
    __shared__ float red[256];
    int tid = threadIdx.x;
    float local_sw = 0.f, local_cw = 0.f;
    for (int i = tid; i < 288; i += 256) {
        float x = spatial_weight[i];
        float v = fmaxf(x, 0.f) + log1pf(expf(-fabsf(x)));
        ws[i] = v;
        local_sw += v;
    }
    for (int i = tid; i < 1024; i += 256) {
        float x = channel_weight[i];   // i = o*32 + c
        float v = fmaxf(x, 0.f) + log1pf(expf(-fabsf(x)));
        int o = i >> 5, c = i & 31;
        ws[288 + c * 32 + o] = v;      // transposed store
        local_cw += v;
    }
    red[tid] = local_sw;
    __syncthreads();
    for (int s = 128; s > 0; s >>= 1) {
        if (tid < s) red[tid] += red[tid + s];
        __syncthreads();
    }
    if (tid == 0) ws[1312] = 1.0f / red[0];
    __syncthreads();
    red[tid] = local_cw;
    __syncthreads();
    for (int s = 128; s > 0; s >>= 1) {
        if (tid < s) red[tid] += red[tid + s];
        __syncthreads();
    }
    if (tid == 0) ws[1313] = 1.0f / red[0];
}

// Per-channel pipelined fused kernel: tile = (b, h) = full row 256 px x 32 ch.
// 8 iterations; iter i: wave w owns channel c = i*4 + w.
//   {ISSUE loads for c(i+1)} {COMPUTE window c(i) from regs, ds_write} barrier {ACC group i}
// -> the next group's 15 f4 global loads stay in flight across the barrier and the
//    LDS-only accumulate phase: the memory pipe is never idle (champion's ~30% stage-2
//    silence was the 4.4 TB/s binder; R13's decorrelation test was confounded by chunk
//    shrink). 1 KB contiguous segments per load instruction (chunk-saturated per R17).
// Stage 2 folded per-iter: wave w owns outputs o = w*8..w*8+7, lane owns 4 px (f4 acc).
// LDS 68 KB -> 2 blocks/CU; edges via __shfl (masked invalid at row ends).
__global__ __launch_bounds__(256) void fused13(
    const float* __restrict__ d,
    const float* __restrict__ cd,
    const float* __restrict__ sp,     // [B,Cin,9,H,W]
    const float* __restrict__ wsbuf,
    const float* __restrict__ bias,   // [32]
    float* __restrict__ out)          // d_out [4,32,256,256] then cd_out
{
    __shared__ float lt[32 * 256];    // nom*inv_sum_sw,  [c][col]
    __shared__ float lc[32 * 256];    // cdsp = den*inv_sum_sw
    __shared__ float lcw[1024];       // [c][o]

    const int plane = 65536;

    // chunked XCD swizzle (1024 % 8 == 0)
    int bid = blockIdx.x;
    bid = (bid & 7) * 128 + (bid >> 3);

    const int h = bid & 255;
    const int b = bid >> 8;

    const int tid = threadIdx.x;

    // cooperative: channel weights -> LDS (consumed after the first barrier)
    #pragma unroll
    for (int i = 0; i < 4; ++i) lcw[i * 256 + tid] = wsbuf[288 + i * 256 + tid];

    const int w    = tid >> 6;        // wave 0..3
    const int lane = tid & 63;
    const int col0 = lane * 4;        // lane's 4 px within the row
    const float inv_sum_sw = wsbuf[1312];
    const bool rowv0 = (h >= 1), rowv2 = (h <= 254);

    f4 spA[9], spB[9], dA[3], dB[3], cA[3], cB[3];
    f4 n2[8], d2[8];
    #pragma unroll
    for (int oi = 0; oi < 8; ++oi)
        #pragma unroll
        for (int j = 0; j < 4; ++j) { n2[oi][j] = 0.f; d2[oi][j] = 0.f; }

#define ISSUE(SPB, DB, CB, ITER) do { \
    const int ci_  = (ITER) * 4 + w; \
    const int bci_ = b * 32 + ci_; \
    const float* __restrict__ spC_ = sp + (size_t)bci_ * 9 * plane + h * 256 + col0; \
    _Pragma("unroll") \
    for (int k_ = 0; k_ < 9; ++k_) \
        SPB[k_] = __builtin_nontemporal_load((const f4*)(spC_ + (size_t)k_ * plane)); \
    const float* __restrict__ dC_  = d  + (size_t)bci_ * plane; \
    const float* __restrict__ cdC_ = cd + (size_t)bci_ * plane; \
    _Pragma("unroll") \
    for (int i_ = 0; i_ < 3; ++i_) { \
        const int hc_ = min(max(h + i_ - 1, 0), 255); \
        DB[i_] = *(const f4*)(dC_  + hc_ * 256 + col0); \
        CB[i_] = *(const f4*)(cdC_ + hc_ * 256 + col0); \
    } \
} while (0)

#define COMPUTE(SPB, DB, CB, ITER) do { \
    const int c_ = (ITER) * 4 + w; \
    float dr_[3][6], cr_[3][6]; \
    _Pragma("unroll") \
    for (int i_ = 0; i_ < 3; ++i_) { \
        dr_[i_][0] = __shfl_up(DB[i_][3], 1); \
        cr_[i_][0] = __shfl_up(CB[i_][3], 1); \
        dr_[i_][5] = __shfl_down(DB[i_][0], 1); \
        cr_[i_][5] = __shfl_down(CB[i_][0], 1); \
        _Pragma("unroll") \
        for (int p_ = 0; p_ < 4; ++p_) { \
            dr_[i_][p_ + 1] = DB[i_][p_]; \
            cr_[i_][p_ + 1] = CB[i_][p_]; \
        } \
    } \
    float swk_[9]; \
    _Pragma("unroll") \
    for (int k_ = 0; k_ < 9; ++k_) swk_[k_] = wsbuf[c_ * 9 + k_]; \
    float nom_[4] = {0.f, 0.f, 0.f, 0.f}, den_[4] = {0.f, 0.f, 0.f, 0.f}; \
    _Pragma("unroll") \
    for (int i_ = 0; i_ < 3; ++i_) { \
        const bool rv_ = (i_ == 0) ? rowv0 : ((i_ == 2) ? rowv2 : true); \
        _Pragma("unroll") \
        for (int j_ = 0; j_ < 3; ++j_) { \
            const int k_ = i_ * 3 + j_; \
            const float s_ = swk_[k_]; \
            _Pragma("unroll") \
            for (int p_ = 0; p_ < 4; ++p_) { \
                const int ww_ = col0 + p_ + j_ - 1; \
                const bool valid_ = rv_ && ((unsigned)ww_ < 256u); \
                const float cdp_ = valid_ ? cr_[i_][p_ + j_] * SPB[k_][p_] : 0.f; \
                nom_[p_] = fmaf(cdp_ * dr_[i_][p_ + j_], s_, nom_[p_]); \
                den_[p_] = fmaf(cdp_, s_, den_[p_]); \
            } \
        } \
    } \
    /* t = cdsp*dsp ~= nom*inv_sum_sw (rel err EPS/(den+EPS)) */ \
    f4 tv_, cv4_; \
    _Pragma("unroll") \
    for (int p_ = 0; p_ < 4; ++p_) { \
        tv_[p_]  = nom_[p_] * inv_sum_sw; \
        cv4_[p_] = den_[p_] * inv_sum_sw; \
    } \
    *(f4*)&lt[c_ * 256 + col0] = tv_; \
    *(f4*)&lc[c_ * 256 + col0] = cv4_; \
} while (0)

#define ACC(ITER) do { \
    _Pragma("unroll") \
    for (int cc_ = (ITER) * 4; cc_ < (ITER) * 4 + 4; ++cc_) { \
        const f4 tq_  = *(const f4*)&lt[cc_ * 256 + col0]; \
        const f4 cq_  = *(const f4*)&lc[cc_ * 256 + col0]; \
        const f4 cwA_ = *(const f4*)&lcw[cc_ * 32 + w * 8]; \
        const f4 cwB_ = *(const f4*)&lcw[cc_ * 32 + w * 8 + 4]; \
        _Pragma("unroll") \
        for (int oi_ = 0; oi_ < 4; ++oi_) { \
            _Pragma("unroll") \
            for (int j_ = 0; j_ < 4; ++j_) { \
                n2[oi_][j_]     = fmaf(tq_[j_], cwA_[oi_], n2[oi_][j_]); \
                d2[oi_][j_]     = fmaf(cq_[j_], cwA_[oi_], d2[oi_][j_]); \
                n2[4 + oi_][j_] = fmaf(tq_[j_], cwB_[oi_], n2[4 + oi_][j_]); \
                d2[4 + oi_][j_] = fmaf(cq_[j_], cwB_[oi_], d2[4 + oi_][j_]); \
            } \
        } \
    } \
} while (0)

    // ---------------- pipelined main: 8 channel-group iterations ----------------
    ISSUE(spA, dA, cA, 0);
    ISSUE(spB, dB, cB, 1); COMPUTE(spA, dA, cA, 0); __syncthreads(); ACC(0);
    ISSUE(spA, dA, cA, 2); COMPUTE(spB, dB, cB, 1); __syncthreads(); ACC(1);
    ISSUE(spB, dB, cB, 3); COMPUTE(spA, dA, cA, 2); __syncthreads(); ACC(2);
    ISSUE(spA, dA, cA, 4); COMPUTE(spB, dB, cB, 3); __syncthreads(); ACC(3);
    ISSUE(spB, dB, cB, 5); COMPUTE(spA, dA, cA, 4); __syncthreads(); ACC(4);
    ISSUE(spA, dA, cA, 6); COMPUTE(spB, dB, cB, 5); __syncthreads(); ACC(5);
    ISSUE(spB, dB, cB, 7); COMPUTE(spA, dA, cA, 6); __syncthreads(); ACC(6);
                           COMPUTE(spB, dB, cB, 7); __syncthreads(); ACC(7);

#undef ISSUE
#undef COMPUTE
#undef ACC

    // ---------------- epilogue: outputs ----------------
    const float inv_sum_cw = wsbuf[1313];
    const int o0 = w * 8;

    #pragma unroll
    for (int oi = 0; oi < 8; ++oi) {
        const float bo = bias[o0 + oi];
        f4 dv, cv;
        #pragma unroll
        for (int j = 0; j < 4; ++j) {
            dv[j] = n2[oi][j] / (d2[oi][j] + EPS) + bo;
            cv[j] = d2[oi][j] * inv_sum_cw;   // STRIDE=1
        }
        const size_t po = (size_t)(b * 32 + o0 + oi) * plane + h * 256 + col0;
        *(f4*)(out + po)           = dv;
        *(f4*)(out + 8388608 + po) = cv;
    }
}

extern "C" void kernel_launch(void* const* d_in, const int* in_sizes, int n_in,
                              void* d_out, int out_size, void* d_ws, size_t ws_size,
                              hipStream_t stream) {
    const float* d    = (const float*)d_in[0];
    const float* cd   = (const float*)d_in[1];
    // d_in[2] = s, d_in[3] = cs : unused in forward
    const float* sp   = (const float*)d_in[4];
    const float* cwt  = (const float*)d_in[5];
    const float* swt  = (const float*)d_in[6];
    const float* bias = (const float*)d_in[7];
    float* out = (float*)d_out;
    float* ws  = (float*)d_ws;

    prep_weights<<<1, 256, 0, stream>>>(cwt, swt, ws);
    fused13<<<1024, 256, 0, stream>>>(d, cd, sp, ws, bias, out);
}